// Round 5
// baseline (279.437 us; speedup 1.0000x reference)
//
#include <hip/hip_runtime.h>
#include <stdint.h>

// Top-K (K=64) per row of [4096, 32768] f32, relu'd, scattered into zeros.
//
// Round-5 design: decouple the write stream from the read stream.
//  - hipMemsetAsync zeroes d_out at fill speed (harness fills measure
//    6.6 TB/s on this box -> ~81 us for 537 MB). Graph-capturable.
//  - Kernel is then a lean READ-ONLY stream: 256 thr/block, 8 blocks/CU.
//    Per element: one float compare (v >= 2.0f). Candidates (~2.3% for
//    N(0,1)) self-append to an LDS list with a per-lane atomicAdd — no
//    ballot/ffs/shfl machinery in the hot loop. Positive floats order
//    correctly as raw unsigned bits, so no key transform either.
//  - Exact 4x8-bit radix select over the M~745 candidates (256-bucket LDS
//    histogram), then scatter winners; ties at the exact 32-bit value are
//    included lowest-index-first via position ranking (matches
//    jax.lax.top_k). List append order doesn't affect the result.
//  - Fallback (M < 64 or M > CAP; statistically never for this input):
//    exact 32-bit radix select over global re-reads with f2o keys,
//    ordered tie-break, explicit relu.

#define LROW   32768
#define NT     256
#define NWAVE  (NT / 64)            // 4
#define ITERS  (LROW / (NT * 4))    // 32
#define KSEL   64u
#define CAP    2048u
#define FCUT   2.0f                 // candidate threshold (value space)

// float bits -> order-preserving uint (used only in the fallback)
__device__ __forceinline__ uint32_t f2o(uint32_t b) {
    return b ^ (uint32_t)(((int32_t)b >> 31) | 0x80000000u);
}
__device__ __forceinline__ float o2f(uint32_t u) {
    uint32_t b = (u & 0x80000000u) ? (u ^ 0x80000000u) : ~u;
    return __uint_as_float(b);
}

// Wave 0 scans hist[nb-1..0] from the top; finds bucket b* with
// cum_before < need <= cum_before + hist[b*]; writes {b*, cum_before, hist[b*]}
// to ctrl[0..2]. Caller syncs before (hist ready) and after (result visible).
__device__ __forceinline__ void wave0_select(uint32_t* ctrl, const uint32_t* hist,
                                             int nb, uint32_t need,
                                             int tid, int lane)
{
    if (tid < 64) {
        uint32_t cum = 0;
        int done = 0;
        for (int base = nb; base > 0 && !done; base -= 64) {
            uint32_t c = hist[base - 1 - lane];   // lane 0 = highest bucket
            uint32_t inc = c;
            #pragma unroll
            for (int off = 1; off < 64; off <<= 1) {
                uint32_t t = __shfl_up(inc, off);
                if (lane >= off) inc += t;
            }
            uint32_t tot = __shfl(inc, 63);
            uint32_t pre = inc - c;
            bool hit = (cum + pre < need) && (cum + pre + c >= need);
            if (hit) {
                ctrl[0] = (uint32_t)(base - 1 - lane);
                ctrl[1] = cum + pre;
                ctrl[2] = c;
            }
            done = (__ballot(hit) != 0ull);
            cum += tot;
        }
    }
}

__global__ __launch_bounds__(NT, 8) void topk_kernel(
    const float* __restrict__ x, float* __restrict__ out)
{
    __shared__ uint32_t cu[CAP];     // candidate keys (raw positive-float bits)
    __shared__ uint32_t cp[CAP];     // candidate positions
    __shared__ uint32_t hist[256];
    __shared__ uint32_t ctrl[64];

    const int tid  = threadIdx.x;
    const int lane = tid & 63;
    const int wid  = tid >> 6;
    const size_t rowoff = (size_t)blockIdx.x * LROW;
    const float4* __restrict__ xin = (const float4*)(x + rowoff);

    if (tid == 0) ctrl[3] = 0u;      // candidate-append counter
    __syncthreads();

    // ---- Phase 0: lean read-only stream + per-lane candidate append ----
    #pragma unroll 4
    for (int j = 0; j < ITERS; ++j) {
        int p = j * NT + tid;        // float4 index
        float4 v = xin[p];
        #pragma unroll
        for (int q = 0; q < 4; ++q) {
            float f = (q == 0) ? v.x : (q == 1) ? v.y : (q == 2) ? v.z : v.w;
            if (f >= FCUT) {
                uint32_t idx = atomicAdd(&ctrl[3], 1u);
                if (idx < CAP) {
                    cu[idx] = __float_as_uint(f);   // positive: bits are ordered
                    cp[idx] = (uint32_t)(p * 4 + q);
                }
            }
        }
    }
    __syncthreads();
    uint32_t M = ctrl[3];

    if (M >= KSEL && M <= CAP) {
        // ---- Main path: exact 4x8-bit radix select over M candidates ----
        uint32_t need = KSEL;
        uint32_t pref = 0;
        uint32_t cnt  = 0;
        #pragma unroll
        for (int L = 3; L >= 0; --L) {
            __syncthreads();
            if (tid < 256) hist[tid] = 0u;
            __syncthreads();
            for (uint32_t i = tid; i < M; i += NT) {
                uint32_t u = cu[i];
                bool inb = (L == 3) || ((u >> ((L + 1) * 8)) == pref);
                if (inb) atomicAdd(&hist[(u >> (L * 8)) & 0xFFu], 1u);
            }
            __syncthreads();
            wave0_select(ctrl, hist, 256, need, tid, lane);
            __syncthreads();
            uint32_t d = ctrl[0], cum = ctrl[1];
            cnt = ctrl[2];
            pref = (pref << 8) | d;
            need = need - cum;        // 1..cnt
        }
        uint32_t T32 = pref;          // exact 64th-largest key (raw bits)
        uint32_t r   = need;          // #(==T32) to include, lowest index first

        // ---- Scatter winners straight from the candidate list ----
        for (uint32_t i = tid; i < M; i += NT) {
            uint32_t u = cu[i];
            if (u > T32) {
                out[rowoff + cp[i]] = __uint_as_float(u);  // >= 2.0 > 0, relu no-op
            } else if (u == T32) {
                bool take = (r == cnt);
                if (!take) {
                    uint32_t myp = cp[i], rank = 0;
                    for (uint32_t j2 = 0; j2 < M; ++j2)
                        rank += (cu[j2] == T32 && cp[j2] < myp);
                    take = (rank < r);
                }
                if (take) out[rowoff + cp[i]] = __uint_as_float(u);
            }
        }
        return;
    }

    // ---- Fallback: exact 32-bit radix over global re-reads (correctness
    //      insurance; statistically never taken for N(0,1) rows) ----
    uint32_t* hist2 = cu;            // 2048-entry histogram in candidate space

    // Level A: bits 31:21
    for (int i = tid; i < 2048; i += NT) hist2[i] = 0u;
    __syncthreads();
    for (int j = 0; j < ITERS; ++j) {
        float4 v = xin[j * NT + tid];
        uint32_t u[4] = { f2o(__float_as_uint(v.x)), f2o(__float_as_uint(v.y)),
                          f2o(__float_as_uint(v.z)), f2o(__float_as_uint(v.w)) };
        #pragma unroll
        for (int q = 0; q < 4; ++q) atomicAdd(&hist2[u[q] >> 21], 1u);
    }
    __syncthreads();
    wave0_select(ctrl, hist2, 2048, KSEL, tid, lane);
    __syncthreads();
    uint32_t bA = ctrl[0], cumA = ctrl[1];
    uint32_t needB = KSEL - cumA;

    // Level B: bits 20:10 within bucket bA
    __syncthreads();
    for (int i = tid; i < 2048; i += NT) hist2[i] = 0u;
    __syncthreads();
    for (int j = 0; j < ITERS; ++j) {
        float4 v = xin[j * NT + tid];
        uint32_t u[4] = { f2o(__float_as_uint(v.x)), f2o(__float_as_uint(v.y)),
                          f2o(__float_as_uint(v.z)), f2o(__float_as_uint(v.w)) };
        #pragma unroll
        for (int q = 0; q < 4; ++q)
            if ((u[q] >> 21) == bA) atomicAdd(&hist2[(u[q] >> 10) & 0x7FFu], 1u);
    }
    __syncthreads();
    wave0_select(ctrl, hist2, 2048, needB, tid, lane);
    __syncthreads();
    uint32_t bB = ctrl[0], cumB = ctrl[1];
    uint32_t P22 = (bA << 11) | bB;
    uint32_t needC = needB - cumB;

    // Level C: bits 9:0 within prefix P22
    __syncthreads();
    for (int i = tid; i < 2048; i += NT) hist2[i] = 0u;
    __syncthreads();
    for (int j = 0; j < ITERS; ++j) {
        float4 v = xin[j * NT + tid];
        uint32_t u[4] = { f2o(__float_as_uint(v.x)), f2o(__float_as_uint(v.y)),
                          f2o(__float_as_uint(v.z)), f2o(__float_as_uint(v.w)) };
        #pragma unroll
        for (int q = 0; q < 4; ++q)
            if ((u[q] >> 10) == P22) atomicAdd(&hist2[u[q] & 0x3FFu], 1u);
    }
    __syncthreads();
    wave0_select(ctrl, hist2, 1024, needC, tid, lane);
    __syncthreads();
    uint32_t bC = ctrl[0], cumC = ctrl[1];
    uint32_t T32f = (P22 << 10) | bC;
    uint32_t r2   = needC - cumC;    // #(==T32f) to include, lowest index first

    // Ordered rank of ==T32f over contiguous chunks (index order), then scatter.
    const int cbase = tid * (LROW / NT);
    uint32_t c = 0;
    for (int j = 0; j < LROW / NT; ++j)
        c += (f2o(__float_as_uint(x[rowoff + cbase + j])) == T32f);
    uint32_t inc = c;
    #pragma unroll
    for (int off = 1; off < 64; off <<= 1) {
        uint32_t t = __shfl_up(inc, off);
        if (lane >= off) inc += t;
    }
    if (lane == 63) ctrl[16 + wid] = inc;
    __syncthreads();
    if (tid < NWAVE) {
        uint32_t v = ctrl[16 + tid];
        uint32_t inc2 = v;
        #pragma unroll
        for (int off = 1; off < NWAVE; off <<= 1) {
            uint32_t t = __shfl_up(inc2, off);
            if (lane >= off) inc2 += t;
        }
        ctrl[16 + tid] = inc2 - v;   // exclusive wave base
    }
    __syncthreads();
    uint32_t rank = ctrl[16 + wid] + (inc - c);
    for (int j = 0; j < LROW / NT; ++j) {
        uint32_t u = f2o(__float_as_uint(x[rowoff + cbase + j]));
        bool take = false;
        if (u > T32f) take = true;
        else if (u == T32f) { take = (rank < r2); rank++; }
        if (take) {
            float v = o2f(u);
            if (v > 0.f) out[rowoff + cbase + j] = v;   // relu; 0 == background
        }
    }
}

extern "C" void kernel_launch(void* const* d_in, const int* in_sizes, int n_in,
                              void* d_out, int out_size, void* d_ws, size_t ws_size,
                              hipStream_t stream)
{
    const float* x = (const float*)d_in[0];
    float* out = (float*)d_out;
    int rows = in_sizes[0] / LROW;   // 4096

    // Zero the output at fill speed (graph-capturable memset node),
    // then run the read-only select+scatter kernel.
    hipMemsetAsync(d_out, 0, (size_t)out_size * sizeof(float), stream);
    topk_kernel<<<rows, NT, 0, stream>>>(x, out);
}

// Round 6
// 245.993 us; speedup vs baseline: 1.1360x; 1.1360x over previous
//
#include <hip/hip_runtime.h>
#include <stdint.h>

// Top-K (K=64) per row of [4096, 32768] f32, relu'd, scattered into zeros.
//
// Round-6: fused single kernel (R5's memset split regressed — rocclr fill on
// 537 MB runs at only 1.65 TB/s), with the streaming loop stripped to
// near-copy form:
//  - 256 thr/block, 8 blocks/CU (17.3 KiB LDS), one block per row.
//  - Hot loop: batch of 4 float4 loads -> 4 nontemporal zero stores -> detect.
//    Detect = 3 v_max + 1 cmp + 1 branch per float4; ~9% of lanes take the
//    branch and do per-element checks + plain per-lane LDS list append.
//    No ballot/ffs/shfl in the stream (that machinery throttled R4).
//  - Exact 4x8-bit radix select over the M~745 candidates (>= 2.0f), scatter
//    <=64 winners; ties at the exact 32-bit value included lowest-index-first
//    (matches jax.lax.top_k).
//  - Fallback (M < 64 or M > CAP; statistically never for N(0,1)): exact
//    32-bit radix select over global re-reads, ordered tie-break, explicit
//    relu. Exactness for ANY input.

#define LROW   32768
#define NT     256
#define NWAVE  (NT / 64)            // 4
#define ITERS  (LROW / (NT * 4))    // 32
#define KSEL   64u
#define CAP    2048u
#define FCUT   2.0f                 // candidate threshold (value space)

typedef float vf4 __attribute__((ext_vector_type(4)));

// float bits -> order-preserving uint (used only in the fallback)
__device__ __forceinline__ uint32_t f2o(uint32_t b) {
    return b ^ (uint32_t)(((int32_t)b >> 31) | 0x80000000u);
}
__device__ __forceinline__ float o2f(uint32_t u) {
    uint32_t b = (u & 0x80000000u) ? (u ^ 0x80000000u) : ~u;
    return __uint_as_float(b);
}

// Wave 0 scans hist[nb-1..0] from the top; finds bucket b* with
// cum_before < need <= cum_before + hist[b*]; writes {b*, cum_before, hist[b*]}
// to ctrl[0..2]. Caller syncs before (hist ready) and after (result visible).
__device__ __forceinline__ void wave0_select(uint32_t* ctrl, const uint32_t* hist,
                                             int nb, uint32_t need,
                                             int tid, int lane)
{
    if (tid < 64) {
        uint32_t cum = 0;
        int done = 0;
        for (int base = nb; base > 0 && !done; base -= 64) {
            uint32_t c = hist[base - 1 - lane];   // lane 0 = highest bucket
            uint32_t inc = c;
            #pragma unroll
            for (int off = 1; off < 64; off <<= 1) {
                uint32_t t = __shfl_up(inc, off);
                if (lane >= off) inc += t;
            }
            uint32_t tot = __shfl(inc, 63);
            uint32_t pre = inc - c;
            bool hit = (cum + pre < need) && (cum + pre + c >= need);
            if (hit) {
                ctrl[0] = (uint32_t)(base - 1 - lane);
                ctrl[1] = cum + pre;
                ctrl[2] = c;
            }
            done = (__ballot(hit) != 0ull);
            cum += tot;
        }
    }
}

__device__ __forceinline__ void detect4(const float4& v, int p4,
                                        uint32_t* cu, uint32_t* cp,
                                        uint32_t* ctrl)
{
    float m = fmaxf(fmaxf(v.x, v.y), fmaxf(v.z, v.w));
    if (m >= FCUT) {                 // ~9% of lanes
        float f[4] = {v.x, v.y, v.z, v.w};
        #pragma unroll
        for (int q = 0; q < 4; ++q) {
            if (f[q] >= FCUT) {
                uint32_t idx = atomicAdd(&ctrl[3], 1u);
                if (idx < CAP) {
                    cu[idx] = __float_as_uint(f[q]);  // positive: bits ordered
                    cp[idx] = (uint32_t)(p4 * 4 + q);
                }
            }
        }
    }
}

__global__ __launch_bounds__(NT, 8) void topk_kernel(
    const float* __restrict__ x, float* __restrict__ out)
{
    __shared__ uint32_t cu[CAP];     // candidate keys (raw positive-float bits)
    __shared__ uint32_t cp[CAP];     // candidate positions
    __shared__ uint32_t hist[256];
    __shared__ uint32_t ctrl[64];

    const int tid  = threadIdx.x;
    const int lane = tid & 63;
    const int wid  = tid >> 6;
    const size_t rowoff = (size_t)blockIdx.x * LROW;
    const float4* __restrict__ xin  = (const float4*)(x + rowoff);
    vf4*          __restrict__ xout = (vf4*)(out + rowoff);

    if (tid == 0) ctrl[3] = 0u;      // candidate-append counter
    __syncthreads();

    // ---- Phase 0: copy-like stream: 4 loads | 4 NT zero-stores | detect ----
    const vf4 z = (vf4)(0.0f);
    for (int j = 0; j < ITERS; j += 4) {
        int p0 = (j + 0) * NT + tid;
        int p1 = (j + 1) * NT + tid;
        int p2 = (j + 2) * NT + tid;
        int p3 = (j + 3) * NT + tid;
        float4 v0 = xin[p0];
        float4 v1 = xin[p1];
        float4 v2 = xin[p2];
        float4 v3 = xin[p3];
        __builtin_nontemporal_store(z, &xout[p0]);
        __builtin_nontemporal_store(z, &xout[p1]);
        __builtin_nontemporal_store(z, &xout[p2]);
        __builtin_nontemporal_store(z, &xout[p3]);
        detect4(v0, p0, cu, cp, ctrl);
        detect4(v1, p1, cu, cp, ctrl);
        detect4(v2, p2, cu, cp, ctrl);
        detect4(v3, p3, cu, cp, ctrl);
    }
    __syncthreads();
    uint32_t M = ctrl[3];

    if (M >= KSEL && M <= CAP) {
        // ---- Main path: exact 4x8-bit radix select over M candidates ----
        uint32_t need = KSEL;
        uint32_t pref = 0;
        uint32_t cnt  = 0;
        #pragma unroll
        for (int L = 3; L >= 0; --L) {
            __syncthreads();
            if (tid < 256) hist[tid] = 0u;
            __syncthreads();
            for (uint32_t i = tid; i < M; i += NT) {
                uint32_t u = cu[i];
                bool inb = (L == 3) || ((u >> ((L + 1) * 8)) == pref);
                if (inb) atomicAdd(&hist[(u >> (L * 8)) & 0xFFu], 1u);
            }
            __syncthreads();
            wave0_select(ctrl, hist, 256, need, tid, lane);
            __syncthreads();
            uint32_t d = ctrl[0], cum = ctrl[1];
            cnt = ctrl[2];
            pref = (pref << 8) | d;
            need = need - cum;        // 1..cnt
        }
        uint32_t T32 = pref;          // exact 64th-largest key (raw bits)
        uint32_t r   = need;          // #(==T32) to include, lowest index first

        // ---- Scatter winners straight from the candidate list ----
        for (uint32_t i = tid; i < M; i += NT) {
            uint32_t u = cu[i];
            if (u > T32) {
                out[rowoff + cp[i]] = __uint_as_float(u);  // >= 2.0 > 0
            } else if (u == T32) {
                bool take = (r == cnt);
                if (!take) {
                    uint32_t myp = cp[i], rank = 0;
                    for (uint32_t j2 = 0; j2 < M; ++j2)
                        rank += (cu[j2] == T32 && cp[j2] < myp);
                    take = (rank < r);
                }
                if (take) out[rowoff + cp[i]] = __uint_as_float(u);
            }
        }
        return;
    }

    // ---- Fallback: exact 32-bit radix over global re-reads (correctness
    //      insurance; statistically never taken for N(0,1) rows) ----
    uint32_t* hist2 = cu;            // 2048-entry histogram in candidate space

    // Level A: bits 31:21
    for (int i = tid; i < 2048; i += NT) hist2[i] = 0u;
    __syncthreads();
    for (int j = 0; j < ITERS; ++j) {
        float4 v = xin[j * NT + tid];
        uint32_t u[4] = { f2o(__float_as_uint(v.x)), f2o(__float_as_uint(v.y)),
                          f2o(__float_as_uint(v.z)), f2o(__float_as_uint(v.w)) };
        #pragma unroll
        for (int q = 0; q < 4; ++q) atomicAdd(&hist2[u[q] >> 21], 1u);
    }
    __syncthreads();
    wave0_select(ctrl, hist2, 2048, KSEL, tid, lane);
    __syncthreads();
    uint32_t bA = ctrl[0], cumA = ctrl[1];
    uint32_t needB = KSEL - cumA;

    // Level B: bits 20:10 within bucket bA
    __syncthreads();
    for (int i = tid; i < 2048; i += NT) hist2[i] = 0u;
    __syncthreads();
    for (int j = 0; j < ITERS; ++j) {
        float4 v = xin[j * NT + tid];
        uint32_t u[4] = { f2o(__float_as_uint(v.x)), f2o(__float_as_uint(v.y)),
                          f2o(__float_as_uint(v.z)), f2o(__float_as_uint(v.w)) };
        #pragma unroll
        for (int q = 0; q < 4; ++q)
            if ((u[q] >> 21) == bA) atomicAdd(&hist2[(u[q] >> 10) & 0x7FFu], 1u);
    }
    __syncthreads();
    wave0_select(ctrl, hist2, 2048, needB, tid, lane);
    __syncthreads();
    uint32_t bB = ctrl[0], cumB = ctrl[1];
    uint32_t P22 = (bA << 11) | bB;
    uint32_t needC = needB - cumB;

    // Level C: bits 9:0 within prefix P22
    __syncthreads();
    for (int i = tid; i < 2048; i += NT) hist2[i] = 0u;
    __syncthreads();
    for (int j = 0; j < ITERS; ++j) {
        float4 v = xin[j * NT + tid];
        uint32_t u[4] = { f2o(__float_as_uint(v.x)), f2o(__float_as_uint(v.y)),
                          f2o(__float_as_uint(v.z)), f2o(__float_as_uint(v.w)) };
        #pragma unroll
        for (int q = 0; q < 4; ++q)
            if ((u[q] >> 10) == P22) atomicAdd(&hist2[u[q] & 0x3FFu], 1u);
    }
    __syncthreads();
    wave0_select(ctrl, hist2, 1024, needC, tid, lane);
    __syncthreads();
    uint32_t bC = ctrl[0], cumC = ctrl[1];
    uint32_t T32f = (P22 << 10) | bC;
    uint32_t r2   = needC - cumC;    // #(==T32f) to include, lowest index first

    // Ordered rank of ==T32f over contiguous chunks (index order), then scatter.
    const int cbase = tid * (LROW / NT);
    uint32_t c = 0;
    for (int j = 0; j < LROW / NT; ++j)
        c += (f2o(__float_as_uint(x[rowoff + cbase + j])) == T32f);
    uint32_t inc = c;
    #pragma unroll
    for (int off = 1; off < 64; off <<= 1) {
        uint32_t t = __shfl_up(inc, off);
        if (lane >= off) inc += t;
    }
    if (lane == 63) ctrl[16 + wid] = inc;
    __syncthreads();
    if (tid < NWAVE) {
        uint32_t v = ctrl[16 + tid];
        uint32_t inc2 = v;
        #pragma unroll
        for (int off = 1; off < NWAVE; off <<= 1) {
            uint32_t t = __shfl_up(inc2, off);
            if (lane >= off) inc2 += t;
        }
        ctrl[16 + tid] = inc2 - v;   // exclusive wave base
    }
    __syncthreads();
    uint32_t rank = ctrl[16 + wid] + (inc - c);
    for (int j = 0; j < LROW / NT; ++j) {
        uint32_t u = f2o(__float_as_uint(x[rowoff + cbase + j]));
        bool take = false;
        if (u > T32f) take = true;
        else if (u == T32f) { take = (rank < r2); rank++; }
        if (take) {
            float v = o2f(u);
            if (v > 0.f) out[rowoff + cbase + j] = v;   // relu; 0 == background
        }
    }
}

extern "C" void kernel_launch(void* const* d_in, const int* in_sizes, int n_in,
                              void* d_out, int out_size, void* d_ws, size_t ws_size,
                              hipStream_t stream)
{
    const float* x = (const float*)d_in[0];
    float* out = (float*)d_out;
    int rows = in_sizes[0] / LROW;   // 4096

    topk_kernel<<<rows, NT, 0, stream>>>(x, out);
}